// Round 12
// baseline (339.186 us; speedup 1.0000x reference)
//
#include <hip/hip_runtime.h>

using v8h = __attribute__((ext_vector_type(8))) _Float16;       // 8 f16 MFMA frag
using v4f = __attribute__((ext_vector_type(4))) float;          // MFMA acc
using v4u = __attribute__((ext_vector_type(4))) unsigned short; // 8B packed
using v8u = __attribute__((ext_vector_type(8))) unsigned short; // 16B copy

// fp32 <-> fp16
__device__ __forceinline__ unsigned short f2h(float x) {
  _Float16 h = (_Float16)x;
  return __builtin_bit_cast(unsigned short, h);
}
__device__ __forceinline__ float h2f(unsigned short u) {
  return (float)__builtin_bit_cast(_Float16, u);
}

// async global -> LDS, 16 bytes per lane (global_load_lds_dwordx4)
__device__ __forceinline__ void gl_lds16(const unsigned short* g, unsigned short* l) {
  __builtin_amdgcn_global_load_lds(
      (const __attribute__((address_space(1))) unsigned int*)g,
      (__attribute__((address_space(3))) unsigned int*)l, 16, 0, 0);
}

// ---------------------------------------------------------------------------
// All three f32 -> f16 conversions in ONE launch. Grid 4224 x 256, exact
// multiples (3072 / 864 / 288 blocks), 8 elems/thread, no guards needed.
// ---------------------------------------------------------------------------
__global__ void cvt3_kernel(const float* __restrict__ X,
                            const float* __restrict__ Wq,
                            const float* __restrict__ Wp,
                            unsigned short* __restrict__ Xb,
                            unsigned short* __restrict__ Wqb,
                            unsigned short* __restrict__ Wpb) {
  const int blk = (int)blockIdx.x;
  const float* src;
  unsigned short* dst;
  int i;
  if (blk < 3072)      { src = X;  dst = Xb;  i = blk * 256 + threadIdx.x; }
  else if (blk < 3936) { src = Wq; dst = Wqb; i = (blk - 3072) * 256 + threadIdx.x; }
  else                 { src = Wp; dst = Wpb; i = (blk - 3936) * 256 + threadIdx.x; }
  const float* p = src + (size_t)i * 8;
  float4 a = *(const float4*)p;
  float4 b = *(const float4*)(p + 4);
  v8u o = {f2h(a.x), f2h(a.y), f2h(a.z), f2h(a.w),
           f2h(b.x), f2h(b.y), f2h(b.z), f2h(b.w)};
  *(v8u*)(dst + (size_t)i * 8) = o;
}

// ---------------------------------------------------------------------------
// Shared 256^2-tile 8-phase MFMA core (verified template): accumulates
// C[256][256] = A-panel . B-panel^T over NT x 64-K steps into acc.
// Prologue + counted-vmcnt loop; fully drained (vmcnt=0) and barrier-aligned
// at exit, so it can be called repeatedly per block (LDS safely reusable).
// ---------------------------------------------------------------------------
__device__ __forceinline__ void mm256_8ph(
    const unsigned short* __restrict__ Abase,
    const unsigned short* __restrict__ Bbase,
    long astr, long bstr, int NT,
    unsigned short* sm, v4f (&acc)[8][4]) {
  const int t    = (int)threadIdx.x;
  const int ln   = t & 63;
  const int wv   = t >> 6;
  const int quad = ln >> 4;
  const int L    = ln & 15;
  const int wm   = wv >> 2;
  const int wn   = wv & 3;

  const int srow = t >> 3;                        // 0..63
  const int scol = ((t & 7) ^ (srow & 7)) * 8;    // shorts
  const unsigned short* Ath = Abase + (long)srow * astr + scol;
  const unsigned short* Bth = Bbase + (long)srow * bstr + scol;
  unsigned short* lth = &sm[t * 8];

  const int l7   = L & 7;
  const int sl0  = ((0 + quad) ^ l7) * 8;
  const int sl1  = ((4 + quad) ^ l7) * 8;
  const int arow = (wm * 128 + L) * 64;
  const int brow = (wn * 64 + L) * 64;

#pragma unroll
  for (int i = 0; i < 8; i++)
#pragma unroll
    for (int j = 0; j < 4; j++) acc[i][j] = (v4f){0.f, 0.f, 0.f, 0.f};

  auto stA = [&](int tile, int h) {
    if (tile >= NT) return;
    const unsigned short* g = Ath + (long)(h * 128) * astr + tile * 64;
    unsigned short* l = lth + (tile & 1) * 32768 + h * 8192;
    gl_lds16(g, l);
    gl_lds16(g + 64 * astr, l + 4096);
  };
  auto stB = [&](int tile, int h) {
    if (tile >= NT) return;
    const unsigned short* g = Bth + (long)(h * 128) * bstr + tile * 64;
    unsigned short* l = lth + (tile & 1) * 32768 + 16384 + h * 8192;
    gl_lds16(g, l);
    gl_lds16(g + 64 * bstr, l + 4096);
  };

  stB(0, 0); stB(0, 1); stA(0, 0); stA(0, 1);
  stB(1, 0); stB(1, 1); stA(1, 0);
  asm volatile("s_waitcnt vmcnt(6)" ::: "memory");
  __builtin_amdgcn_s_barrier();
  __builtin_amdgcn_sched_barrier(0);

#pragma unroll 2
  for (int kt = 0; kt < NT; ++kt) {
    const unsigned short* sA = &sm[(kt & 1) * 32768];
    const unsigned short* sB = sA + 16384;
    v8h af[4][2], b0[2][2], b1[2][2];

    // ---- phase 1: (mq0, nh0)
#pragma unroll
    for (int i = 0; i < 4; i++) {
      af[i][0] = *(const v8h*)&sA[arow + i * 1024 + sl0];
      af[i][1] = *(const v8h*)&sA[arow + i * 1024 + sl1];
    }
#pragma unroll
    for (int j = 0; j < 2; j++) {
      b0[j][0] = *(const v8h*)&sB[brow + j * 1024 + sl0];
      b0[j][1] = *(const v8h*)&sB[brow + j * 1024 + sl1];
    }
    stA(kt + 1, 1);
    __builtin_amdgcn_s_barrier();
    asm volatile("s_waitcnt lgkmcnt(0)" ::: "memory");
    __builtin_amdgcn_sched_barrier(0);
    __builtin_amdgcn_s_setprio(1);
#pragma unroll
    for (int i = 0; i < 4; i++)
#pragma unroll
      for (int j = 0; j < 2; j++) {
        acc[i][j] = __builtin_amdgcn_mfma_f32_16x16x32_f16(af[i][0], b0[j][0], acc[i][j], 0, 0, 0);
        acc[i][j] = __builtin_amdgcn_mfma_f32_16x16x32_f16(af[i][1], b0[j][1], acc[i][j], 0, 0, 0);
      }
    __builtin_amdgcn_s_setprio(0);
    __builtin_amdgcn_s_barrier();
    __builtin_amdgcn_sched_barrier(0);

    // ---- phase 2: (mq0, nh1)
#pragma unroll
    for (int j = 0; j < 2; j++) {
      b1[j][0] = *(const v8h*)&sB[brow + 2048 + j * 1024 + sl0];
      b1[j][1] = *(const v8h*)&sB[brow + 2048 + j * 1024 + sl1];
    }
    __builtin_amdgcn_s_barrier();
    asm volatile("s_waitcnt lgkmcnt(0)" ::: "memory");
    __builtin_amdgcn_sched_barrier(0);
    __builtin_amdgcn_s_setprio(1);
#pragma unroll
    for (int i = 0; i < 4; i++)
#pragma unroll
      for (int j = 0; j < 2; j++) {
        acc[i][2 + j] = __builtin_amdgcn_mfma_f32_16x16x32_f16(af[i][0], b1[j][0], acc[i][2 + j], 0, 0, 0);
        acc[i][2 + j] = __builtin_amdgcn_mfma_f32_16x16x32_f16(af[i][1], b1[j][1], acc[i][2 + j], 0, 0, 0);
      }
    __builtin_amdgcn_s_setprio(0);
    __builtin_amdgcn_s_barrier();
    __builtin_amdgcn_sched_barrier(0);

    // ---- phase 3: (mq1, nh1)
#pragma unroll
    for (int i = 0; i < 4; i++) {
      af[i][0] = *(const v8h*)&sA[arow + 4096 + i * 1024 + sl0];
      af[i][1] = *(const v8h*)&sA[arow + 4096 + i * 1024 + sl1];
    }
    stB(kt + 2, 0);
    __builtin_amdgcn_s_barrier();
    asm volatile("s_waitcnt lgkmcnt(0)" ::: "memory");
    __builtin_amdgcn_sched_barrier(0);
    __builtin_amdgcn_s_setprio(1);
#pragma unroll
    for (int i = 0; i < 4; i++)
#pragma unroll
      for (int j = 0; j < 2; j++) {
        acc[4 + i][2 + j] = __builtin_amdgcn_mfma_f32_16x16x32_f16(af[i][0], b1[j][0], acc[4 + i][2 + j], 0, 0, 0);
        acc[4 + i][2 + j] = __builtin_amdgcn_mfma_f32_16x16x32_f16(af[i][1], b1[j][1], acc[4 + i][2 + j], 0, 0, 0);
      }
    __builtin_amdgcn_s_setprio(0);
    __builtin_amdgcn_s_barrier();
    __builtin_amdgcn_sched_barrier(0);

    // ---- phase 4: (mq1, nh0)
    stB(kt + 2, 1);
    stA(kt + 2, 0);
    __builtin_amdgcn_s_barrier();
    __builtin_amdgcn_sched_barrier(0);
    __builtin_amdgcn_s_setprio(1);
#pragma unroll
    for (int i = 0; i < 4; i++)
#pragma unroll
      for (int j = 0; j < 2; j++) {
        acc[4 + i][j] = __builtin_amdgcn_mfma_f32_16x16x32_f16(af[i][0], b0[j][0], acc[4 + i][j], 0, 0, 0);
        acc[4 + i][j] = __builtin_amdgcn_mfma_f32_16x16x32_f16(af[i][1], b0[j][1], acc[4 + i][j], 0, 0, 0);
      }
    __builtin_amdgcn_s_setprio(0);
    if (kt + 2 < NT)      { asm volatile("s_waitcnt vmcnt(6)" ::: "memory"); }
    else if (kt + 1 < NT) { asm volatile("s_waitcnt vmcnt(0)" ::: "memory"); }
    __builtin_amdgcn_s_barrier();
    __builtin_amdgcn_sched_barrier(0);
  }
}

// ---------------------------------------------------------------------------
// QK projection: 256x256 tile, 8-phase core. Grid (6, 32) = 192 blocks.
// ---------------------------------------------------------------------------
__global__ __launch_bounds__(512, 2)
void qkv8_kernel(const unsigned short* __restrict__ A,
                 const unsigned short* __restrict__ Bw,
                 unsigned short* __restrict__ QK) {
  __shared__ unsigned short sm[65536];  // 128 KB
  const int t    = (int)threadIdx.x;
  const int ln   = t & 63;
  const int wv   = t >> 6;
  const int quad = ln >> 4;
  const int L    = ln & 15;
  const int wm   = wv >> 2;
  const int wn   = wv & 3;
  const long m0  = (long)blockIdx.y * 256;
  const long n0  = (long)blockIdx.x * 256;

  v4f acc[8][4];
  mm256_8ph(A + m0 * 768, Bw + n0 * 768, 768, 768, 12, sm, acc);

#pragma unroll
  for (int mi = 0; mi < 8; mi++) {
    const long row = m0 + wm * 128 + (mi >> 2) * 64 + (mi & 3) * 16 + quad * 4;
#pragma unroll
    for (int nj = 0; nj < 4; nj++) {
      const long col = n0 + wn * 64 + nj * 16 + L;
#pragma unroll
      for (int r = 0; r < 4; r++)
        QK[(row + r) * 1536 + col] = f2h(acc[mi][nj][r]);
    }
  }
}

// ---------------------------------------------------------------------------
// f16 GEMM, m97 recipe (output projection): C[m,n] = sum_k A[m,k]*Bw[n,k],
// 128x128 tile, BK=32, f32 store. Grid (6,64) = 384 blocks, 2+/CU (8KB LDS).
// Measured faster than the 96-block 256^2 variant (R5 vs R6 A/B: -4 us).
// ---------------------------------------------------------------------------
__global__ __launch_bounds__(256, 2)
void gemm_proj_kernel(const unsigned short* __restrict__ A,
                      const unsigned short* __restrict__ Bw,
                      float* __restrict__ C) {
  __shared__ unsigned short As[4096];
  __shared__ unsigned short Bs[4096];

  const int t    = threadIdx.x;
  const int ln   = t & 63;
  const int wv   = t >> 6;
  const int quad = ln >> 4;
  const int L    = ln & 15;
  const int wm   = (wv >> 1) * 64;
  const int wn   = (wv & 1) * 64;
  const long m0  = (long)blockIdx.y * 128;
  const long n0  = (long)blockIdx.x * 128;

  v4f acc[4][4];
#pragma unroll
  for (int i = 0; i < 4; i++)
#pragma unroll
    for (int j = 0; j < 4; j++) acc[i][j] = (v4f){0.f, 0.f, 0.f, 0.f};

  const int ar = t >> 2;
  const int ac = (t & 3) * 8;
  const unsigned short* Ag = A + (m0 + ar) * 768 + ac;
  const unsigned short* Bg = Bw + (n0 + ar) * 768 + ac;
  unsigned short* la = &As[t * 8];
  unsigned short* lb = &Bs[t * 8];
  const long rowskip = 64L * 768;

  for (int k0 = 0; k0 < 768; k0 += 32) {
    gl_lds16(Ag + k0, la);
    gl_lds16(Ag + rowskip + k0, la + 2048);
    gl_lds16(Bg + k0, lb);
    gl_lds16(Bg + rowskip + k0, lb + 2048);
    __syncthreads();

    v8h af[4], bfr[4];
#pragma unroll
    for (int i = 0; i < 4; i++)
      af[i] = *(const v8h*)(&As[(wm + i * 16 + L) * 32 + quad * 8]);
#pragma unroll
    for (int j = 0; j < 4; j++)
      bfr[j] = *(const v8h*)(&Bs[(wn + j * 16 + L) * 32 + quad * 8]);
#pragma unroll
    for (int i = 0; i < 4; i++)
#pragma unroll
      for (int j = 0; j < 4; j++)
        acc[i][j] = __builtin_amdgcn_mfma_f32_16x16x32_f16(af[i], bfr[j], acc[i][j], 0, 0, 0);
    __syncthreads();
  }

#pragma unroll
  for (int i = 0; i < 4; i++)
#pragma unroll
    for (int j = 0; j < 4; j++)
#pragma unroll
      for (int r = 0; r < 4; r++) {
        long row = m0 + wm + i * 16 + quad * 4 + r;
        long col = n0 + wn + j * 16 + L;
        C[row * 768 + col] = acc[i][j][r];
      }
}

// ---------------------------------------------------------------------------
// COMBINED score + V-projection, 256^2 8-phase core, repacked to EXACTLY 256
// blocks (one round, 1 block/CU):
//   x < 96   : V-projection tile (NT=12) -> VT transposed [d][kv].
//   96..207  : 3 chained score tiles (s = (x-96)*3 .. +2), NT=4 each.
//   208..255 : 2 chained score tiles (s = 336 + (x-208)*2 .. +1).
// Chaining is safe: mm256_8ph exits vmcnt-drained and barrier-aligned, and
// the epilogue touches only global memory, so the next rep's LDS staging
// cannot race prior reads. Consecutive packed-tri slots often share the
// I-panel -> A re-reads hit L2.
// ---------------------------------------------------------------------------
__global__ __launch_bounds__(512, 2)
void scv8_kernel(const unsigned short* __restrict__ QK,
                 const unsigned short* __restrict__ Xb,
                 const unsigned short* __restrict__ Wq,
                 unsigned short* __restrict__ Sc,
                 unsigned short* __restrict__ VT) {
  __shared__ unsigned short sm[65536];  // 128 KB
  const int t    = (int)threadIdx.x;
  const int ln   = t & 63;
  const int wv   = t >> 6;
  const int quad = ln >> 4;
  const int L    = ln & 15;
  const int wm   = wv >> 2;
  const int wn   = wv & 3;

  const int x = (int)blockIdx.x;
  v4f acc[8][4];

  if (x < 96) {
    // ---- V-projection tile ----
    const int mt = x & 31;
    const int nt = x >> 5;
    mm256_8ph(Xb + (long)mt * 256 * 768, Wq + (long)(1536 + nt * 256) * 768,
              768, 768, 12, sm, acc);
#pragma unroll
    for (int mi = 0; mi < 8; mi++) {
      const long token = (long)mt * 256 + wm * 128 + (mi >> 2) * 64 + (mi & 3) * 16 + quad * 4;
      const int b  = (int)(token >> 11);
      const int tk = (int)(token & 2047);
#pragma unroll
      for (int nj = 0; nj < 4; nj++) {
        const int colp = nt * 256 + wn * 64 + nj * 16 + L;
        const int h    = colp >> 8;
        const int d    = colp & 255;
        v4u val = {f2h(acc[mi][nj][0]), f2h(acc[mi][nj][1]),
                   f2h(acc[mi][nj][2]), f2h(acc[mi][nj][3])};
        *(v4u*)(&VT[((long)(b * 3 + h) * 256 + d) * 2048 + tk]) = val;
      }
    }
  } else {
    // ---- chained score tiles ----
    const int idx = x - 96;
    int s0, nrep;
    if (idx < 112) { s0 = idx * 3;              nrep = 3; }
    else           { s0 = 336 + (idx - 112) * 2; nrep = 2; }

    for (int rep = 0; rep < nrep; ++rep) {
      const int s  = s0 + rep;
      const int bh = s / 36;
      int slot = s % 36, Ihi = 0;
      while (slot >= Ihi + 1) { slot -= Ihi + 1; Ihi++; }
      const int Jhi = slot;
      const int b = bh / 3, h = bh % 3;

      mm256_8ph(QK + ((long)b * 2048 + Ihi * 256) * 1536 + h * 256,
                QK + ((long)b * 2048 + Jhi * 256) * 1536 + 768 + h * 256,
                1536, 1536, 4, sm, acc);

      const int i128 = 2 * Ihi + wm;
      const int j128 = 2 * Jhi + (wn >> 1);
      if (j128 <= i128) {  // skip above-diagonal sub-tile on diagonal tiles
        unsigned short* Sb = Sc + ((long)bh * 136 + (long)i128 * (i128 + 1) / 2 + j128) * 16384;
#pragma unroll
        for (int mi = 0; mi < 8; mi++) {
          const int subrow = (mi >> 2) * 64 + (mi & 3) * 16 + quad * 4;
#pragma unroll
          for (int nj = 0; nj < 4; nj++) {
            const int subcol = (wn & 1) * 64 + nj * 16 + L;
#pragma unroll
            for (int r = 0; r < 4; r++)
              Sb[(subrow + r) * 128 + subcol] = f2h(acc[mi][nj][r]);
          }
        }
      }
    }
  }
}

// ---------------------------------------------------------------------------
// FUSED online-softmax + PV + store (LDS-staged V, TRIPLE-buffered, ONE
// barrier per step) + DEFER-MAX (T13, THR=8). Grid (16, 12), 512 thr =
// 8 waves; pair (p, 15-p) -> 17 steps balanced.
// ---------------------------------------------------------------------------
__global__ __launch_bounds__(512, 1)
void pvf_kernel(const unsigned short* __restrict__ Sc,
                const unsigned short* __restrict__ VT,
                unsigned short* __restrict__ AO) {
  __shared__ unsigned short sm[49152];  // 3 x 32KB V triple-buffer
  __shared__ float fbuf[128];           // per-wave 16-float alpha/inv slices

  const int t    = (int)threadIdx.x;
  const int ln   = t & 63;
  const int wv   = t >> 6;     // 0..7
  const int quad = ln >> 4;
  const int L    = ln & 15;

  const int p  = (int)blockIdx.x >> 1;
  const int nh = (int)blockIdx.x & 1;
  const int bh = (int)blockIdx.y;
  const int b  = bh / 3, h = bh % 3;

  const unsigned short* VTb = VT + ((long)(bh * 256 + nh * 128)) * 2048;
  const int rloc = wv * 16 + L;  // local Q-row this lane owns for softmax

  auto stageV = [&](int jj, unsigned short* base) {
#pragma unroll
    for (int pp = 0; pp < 4; pp++) {
      const int sidx = pp * 512 + t;        // 0..2047
      const int d    = sidx >> 4;
      const int ph   = sidx & 15;
      gl_lds16(VTb + (long)d * 2048 + jj * 128 + ((ph ^ (d & 7)) * 8),
               base + sidx * 8);
    }
  };

  for (int sel = 0; sel < 2; ++sel) {
    const int i = sel ? (15 - p) : p;
    const long Sbase = ((long)bh * 136 + (long)i * (i + 1) / 2) * 16384;

    v4f acc[8];
#pragma unroll
    for (int n = 0; n < 8; n++) acc[n] = (v4f){0.f, 0.f, 0.f, 0.f};
    float m_run = -1e30f, l_run = 0.f;

    // prologue: S(0) -> regs, V(0) -> buf0, V(1) -> buf1
    v8u s_cur[4], s_nxt[4];
    {
      const unsigned short* Sp = Sc + Sbase + (long)rloc * 128;
#pragma unroll
      for (int ks = 0; ks < 4; ks++)
        s_cur[ks] = *(const v8u*)(Sp + ks * 32 + quad * 8);
      __builtin_amdgcn_sched_barrier(0);
      stageV(0, &sm[0]);
      if (i >= 1) stageV(1, &sm[16384]);
      __builtin_amdgcn_sched_barrier(0);
    }

    for (int j = 0; j <= i; ++j) {
      const bool last = (j == i);  // wave-uniform
      if (!last) {
        const unsigned short* Sp = Sc + Sbase + (long)(j + 1) * 16384 + (long)rloc * 128;
#pragma unroll
        for (int ks = 0; ks < 4; ks++)
          s_nxt[ks] = *(const v8u*)(Sp + ks * 32 + quad * 8);
      }
      __builtin_amdgcn_sched_barrier(0);
      // counted wait: V(j) drained before signaling via barrier
      if (last)        { asm volatile("s_waitcnt vmcnt(0)" ::: "memory"); }
      else if (j == 0) { asm volatile("s_waitcnt vmcnt(8)" ::: "memory"); }
      else             { asm volatile("s_waitcnt vmcnt(12)" ::: "memory"); }
      __builtin_amdgcn_s_barrier();
      __builtin_amdgcn_sched_barrier(0);
      // stage V(j+2) AFTER the barrier: its target buf was last read at
      // step j-1, which every wave completed before this barrier.
      if (j + 2 <= i) stageV(j + 2, &sm[((j + 2) % 3) * 16384]);
      __builtin_amdgcn_sched_barrier(0);

      // ---- online softmax on s_cur (raw scores * 1/16) ----
      float pv[4][8];
      float mx = -1e30f;
      if (last) {  // diagonal tile: causal mask c <= r (local)
#pragma unroll
        for (int ks = 0; ks < 4; ks++)
#pragma unroll
          for (int e = 0; e < 8; e++) {
            const bool valid = (ks * 32 + quad * 8 + e) <= rloc;
            const float f = valid ? h2f(s_cur[ks][e]) * 0.0625f : -1e30f;
            pv[ks][e] = f;
            mx = fmaxf(mx, f);
          }
      } else {
#pragma unroll
        for (int ks = 0; ks < 4; ks++)
#pragma unroll
          for (int e = 0; e < 8; e++) {
            const float f = h2f(s_cur[ks][e]) * 0.0625f;
            pv[ks][e] = f;
            mx = fmaxf(mx, f);
          }
      }
      mx = fmaxf(mx, __shfl_xor(mx, 16));
      mx = fmaxf(mx, __shfl_xor(mx, 32));

      // defer-max: keep old running max if growth <= 8 (wave-uniform)
      const bool keepm = __all(mx <= m_run + 8.f);
      float alpha = 1.f;
      if (!keepm) {
        const float m_new = fmaxf(m_run, mx);
        alpha = __expf(m_run - m_new);
        m_run = m_new;
      }

      float sum = 0.f;
      v8h pa[4];
#pragma unroll
      for (int ks = 0; ks < 4; ks++) {
        v8h ph16;
#pragma unroll
        for (int e = 0; e < 8; e++) {
          const float pe = __expf(pv[ks][e] - m_run);  // masked -> exp(-huge)=0
          sum += pe;
          ph16[e] = (_Float16)pe;
        }
        pa[ks] = ph16;
      }
      sum += __shfl_xor(sum, 16);
      sum += __shfl_xor(sum, 32);

      if (keepm) {
        l_run = l_run + sum;
      } else {
        l_run = l_run * alpha + sum;
        // alpha transpose: P-row layout (row=L) -> acc-row layout (quad*4+r)
        if (quad == 0) fbuf[wv * 16 + L] = alpha;
        asm volatile("s_waitcnt lgkmcnt(0)" ::: "memory");
        __builtin_amdgcn_sched_barrier(0);
        const float a0 = fbuf[wv * 16 + quad * 4 + 0];
        const float a1 = fbuf[wv * 16 + quad * 4 + 1];
        const float a2 = fbuf[wv * 16 + quad * 4 + 2];
        const float a3 = fbuf[wv * 16 + quad * 4 + 3];
#pragma unroll
        for (int n = 0; n < 8; n++) {
          acc[n][0] *= a0; acc[n][1] *= a1; acc[n][2] *= a2; acc[n][3] *= a3;
        }
      }

      // ---- PV MFMA from swizzled LDS buf j%3 (no trailing barrier) ----
      const unsigned short* vb = &sm[(j % 3) * 16384];
      const int dx = L & 7;  // (nfc*16+L)&7 == L&7
#pragma unroll
      for (int nfc = 0; nfc < 8; nfc++) {
        const int dbase = (nfc * 16 + L) * 128;
        v8h v0 = *(const v8h*)&vb[dbase + ((0 + quad) ^ dx) * 8];
        v8h v1 = *(const v8h*)&vb[dbase + ((4 + quad) ^ dx) * 8];
        v8h v2 = *(const v8h*)&vb[dbase + ((8 + quad) ^ dx) * 8];
        v8h v3 = *(const v8h*)&vb[dbase + ((12 + quad) ^ dx) * 8];
        acc[nfc] = __builtin_amdgcn_mfma_f32_16x16x32_f16(pa[0], v0, acc[nfc], 0, 0, 0);
        acc[nfc] = __builtin_amdgcn_mfma_f32_16x16x32_f16(pa[1], v1, acc[nfc], 0, 0, 0);
        acc[nfc] = __builtin_amdgcn_mfma_f32_16x16x32_f16(pa[2], v2, acc[nfc], 0, 0, 0);
        acc[nfc] = __builtin_amdgcn_mfma_f32_16x16x32_f16(pa[3], v3, acc[nfc], 0, 0, 0);
      }

#pragma unroll
      for (int ks = 0; ks < 4; ks++) s_cur[ks] = s_nxt[ks];
    }

    // finalize: divide by l (transpose inv like alpha) and store f16 to AO
    const float inv = 1.0f / l_run;
    if (quad == 0) fbuf[wv * 16 + L] = inv;
    asm volatile("s_waitcnt lgkmcnt(0)" ::: "memory");
    __builtin_amdgcn_sched_barrier(0);
    const float i0 = fbuf[wv * 16 + quad * 4 + 0];
    const float i1 = fbuf[wv * 16 + quad * 4 + 1];
    const float i2 = fbuf[wv * 16 + quad * 4 + 2];
    const float i3 = fbuf[wv * 16 + quad * 4 + 3];

    unsigned short* Ob = AO + ((long)b * 2048 + (long)i * 128 + wv * 16 + quad * 4) * 768
                            + h * 256 + nh * 128 + L;
#pragma unroll
    for (int n = 0; n < 8; n++) {
      Ob[0 * 768 + n * 16] = f2h(acc[n][0] * i0);
      Ob[1 * 768 + n * 16] = f2h(acc[n][1] * i1);
      Ob[2 * 768 + n * 16] = f2h(acc[n][2] * i2);
      Ob[3 * 768 + n * 16] = f2h(acc[n][3] * i3);
    }
    __builtin_amdgcn_s_barrier();  // all V-buf reads done before next sel
  }
}

// ---------------------------------------------------------------------------
extern "C" void kernel_launch(void* const* d_in, const int* in_sizes, int n_in,
                              void* d_out, int out_size, void* d_ws, size_t ws_size,
                              hipStream_t stream) {
  const float* X     = (const float*)d_in[0];  // [4,2048,768] f32
  const float* Wqkv  = (const float*)d_in[1];  // [2304,768]   f32
  const float* Wproj = (const float*)d_in[2];  // [768,768]    f32
  float* out = (float*)d_out;                  // [4,2048,768] f32

  const size_t SZ_QK = (size_t)8192 * 1536 * 2;       // 25.2 MB
  const size_t SZ_VT = (size_t)3072 * 2048 * 2;       // 12.6 MB
  const size_t SZ_SC = (size_t)12 * 136 * 16384 * 2;  // 53.5 MB
  const size_t SZ_AO = (size_t)8192 * 768 * 2;        // 12.6 MB
  const size_t SZ_WQ = (size_t)2304 * 768 * 2;        //  3.5 MB

  char* ws = (char*)d_ws;
  unsigned short* QKb = (unsigned short*)ws;
  unsigned short* VTb = (unsigned short*)(ws + SZ_QK);
  unsigned short* Scb = (unsigned short*)(ws + SZ_QK + SZ_VT);
  unsigned short* AOb = (unsigned short*)(ws + SZ_QK + SZ_VT + SZ_SC);
  unsigned short* Xb  = AOb;  // alias: Xb dead after scv8; AO written by pvf (later)
  unsigned short* Wqb = (unsigned short*)(ws + SZ_QK + SZ_VT + SZ_SC + SZ_AO);
  unsigned short* Wpb = (unsigned short*)(ws + SZ_QK + SZ_VT + SZ_SC + SZ_AO + SZ_WQ);

  dim3 blk(256, 1, 1);
  // 0) one-time f32 -> f16 conversions (single launch)
  cvt3_kernel<<<dim3(4224, 1, 1), blk, 0, stream>>>(X, Wqkv, Wproj, Xb, Wqb, Wpb);
  // 1) Q,K projection, 256^2 8-phase schedule, one round
  qkv8_kernel<<<dim3(6, 32, 1), dim3(512, 1, 1), 0, stream>>>(Xb, Wqb, QKb);
  // 2) score tiles (chained 2-3/block) + V projection, EXACTLY 256 blocks
  scv8_kernel<<<dim3(256, 1, 1), dim3(512, 1, 1), 0, stream>>>(QKb, Xb, Wqb, Scb, VTb);
  // 3) fused online-softmax + PV + store (triple-buffer V, defer-max)
  pvf_kernel<<<dim3(16, 12, 1), dim3(512, 1, 1), 0, stream>>>(Scb, VTb, AOb);
  // 4) output projection, m97 128^2, 384 blocks 2/CU (measured faster, R5)
  gemm_proj_kernel<<<dim3(6, 64, 1), blk, 0, stream>>>(AOb, Wpb, out);
}

// Round 13
// 218.226 us; speedup vs baseline: 1.5543x; 1.5543x over previous
//
#include <hip/hip_runtime.h>

using v8h = __attribute__((ext_vector_type(8))) _Float16;       // 8 f16 MFMA frag
using v4f = __attribute__((ext_vector_type(4))) float;          // MFMA acc
using v4u = __attribute__((ext_vector_type(4))) unsigned short; // 8B packed
using v8u = __attribute__((ext_vector_type(8))) unsigned short; // 16B copy

// fp32 <-> fp16
__device__ __forceinline__ unsigned short f2h(float x) {
  _Float16 h = (_Float16)x;
  return __builtin_bit_cast(unsigned short, h);
}
__device__ __forceinline__ float h2f(unsigned short u) {
  return (float)__builtin_bit_cast(_Float16, u);
}

// async global -> LDS, 16 bytes per lane (global_load_lds_dwordx4)
__device__ __forceinline__ void gl_lds16(const unsigned short* g, unsigned short* l) {
  __builtin_amdgcn_global_load_lds(
      (const __attribute__((address_space(1))) unsigned int*)g,
      (__attribute__((address_space(3))) unsigned int*)l, 16, 0, 0);
}

// ---------------------------------------------------------------------------
// All three f32 -> f16 conversions in ONE launch. Grid 4224 x 256, exact
// multiples (3072 / 864 / 288 blocks), 8 elems/thread, no guards needed.
// ---------------------------------------------------------------------------
__global__ void cvt3_kernel(const float* __restrict__ X,
                            const float* __restrict__ Wq,
                            const float* __restrict__ Wp,
                            unsigned short* __restrict__ Xb,
                            unsigned short* __restrict__ Wqb,
                            unsigned short* __restrict__ Wpb) {
  const int blk = (int)blockIdx.x;
  const float* src;
  unsigned short* dst;
  int i;
  if (blk < 3072)      { src = X;  dst = Xb;  i = blk * 256 + threadIdx.x; }
  else if (blk < 3936) { src = Wq; dst = Wqb; i = (blk - 3072) * 256 + threadIdx.x; }
  else                 { src = Wp; dst = Wpb; i = (blk - 3936) * 256 + threadIdx.x; }
  const float* p = src + (size_t)i * 8;
  float4 a = *(const float4*)p;
  float4 b = *(const float4*)(p + 4);
  v8u o = {f2h(a.x), f2h(a.y), f2h(a.z), f2h(a.w),
           f2h(b.x), f2h(b.y), f2h(b.z), f2h(b.w)};
  *(v8u*)(dst + (size_t)i * 8) = o;
}

// ---------------------------------------------------------------------------
// QK projection: 256x256 tile, BK=64, 512 thr = 8 waves (2M x 4N), 8-phase
// counted-vmcnt schedule + XOR swizzle + setprio. C = A.Bw^T, K=768.
// f16 store ldc 1536. Grid (6, 32) = 192 blocks, one round at 1 block/CU.
// ---------------------------------------------------------------------------
__global__ __launch_bounds__(512, 2)
void qkv8_kernel(const unsigned short* __restrict__ A,
                 const unsigned short* __restrict__ Bw,
                 unsigned short* __restrict__ QK) {
  __shared__ unsigned short sm[65536];  // 128 KB
  const int t    = (int)threadIdx.x;
  const int ln   = t & 63;
  const int wv   = t >> 6;
  const int quad = ln >> 4;
  const int L    = ln & 15;
  const int wm   = wv >> 2;   // 0..1 -> 128-row half of the 256-row tile
  const int wn   = wv & 3;    // 0..3 -> 64-col stripe
  const long m0  = (long)blockIdx.y * 256;
  const long n0  = (long)blockIdx.x * 256;

  const int srow = t >> 3;                        // 0..63
  const int scol = ((t & 7) ^ (srow & 7)) * 8;    // shorts
  const unsigned short* Ath = A + (m0 + srow) * 768 + scol;
  const unsigned short* Bth = Bw + (n0 + srow) * 768 + scol;
  unsigned short* lth = &sm[t * 8];

  const int l7   = L & 7;
  const int sl0  = ((0 + quad) ^ l7) * 8;   // ks=0, shorts
  const int sl1  = ((4 + quad) ^ l7) * 8;   // ks=1
  const int arow = (wm * 128 + L) * 64;     // shorts
  const int brow = (wn * 64 + L) * 64;      // shorts

  v4f acc[8][4];
#pragma unroll
  for (int i = 0; i < 8; i++)
#pragma unroll
    for (int j = 0; j < 4; j++) acc[i][j] = (v4f){0.f, 0.f, 0.f, 0.f};

  auto stA = [&](int tile, int h) {
    if (tile >= 12) return;
    const unsigned short* g = Ath + (h * 128) * 768 + tile * 64;
    unsigned short* l = lth + (tile & 1) * 32768 + h * 8192;
    gl_lds16(g, l);
    gl_lds16(g + 64 * 768, l + 4096);
  };
  auto stB = [&](int tile, int h) {
    if (tile >= 12) return;
    const unsigned short* g = Bth + (h * 128) * 768 + tile * 64;
    unsigned short* l = lth + (tile & 1) * 32768 + 16384 + h * 8192;
    gl_lds16(g, l);
    gl_lds16(g + 64 * 768, l + 4096);
  };

  stB(0, 0); stB(0, 1); stA(0, 0); stA(0, 1);
  stB(1, 0); stB(1, 1); stA(1, 0);
  asm volatile("s_waitcnt vmcnt(6)" ::: "memory");
  __builtin_amdgcn_s_barrier();
  __builtin_amdgcn_sched_barrier(0);

#pragma unroll 2
  for (int kt = 0; kt < 12; ++kt) {
    const unsigned short* sA = &sm[(kt & 1) * 32768];
    const unsigned short* sB = sA + 16384;
    v8h af[4][2], b0[2][2], b1[2][2];

    // ---- phase 1: (mq0, nh0)
#pragma unroll
    for (int i = 0; i < 4; i++) {
      af[i][0] = *(const v8h*)&sA[arow + i * 1024 + sl0];
      af[i][1] = *(const v8h*)&sA[arow + i * 1024 + sl1];
    }
#pragma unroll
    for (int j = 0; j < 2; j++) {
      b0[j][0] = *(const v8h*)&sB[brow + j * 1024 + sl0];
      b0[j][1] = *(const v8h*)&sB[brow + j * 1024 + sl1];
    }
    stA(kt + 1, 1);
    __builtin_amdgcn_s_barrier();
    asm volatile("s_waitcnt lgkmcnt(0)" ::: "memory");
    __builtin_amdgcn_sched_barrier(0);
    __builtin_amdgcn_s_setprio(1);
#pragma unroll
    for (int i = 0; i < 4; i++)
#pragma unroll
      for (int j = 0; j < 2; j++) {
        acc[i][j] = __builtin_amdgcn_mfma_f32_16x16x32_f16(af[i][0], b0[j][0], acc[i][j], 0, 0, 0);
        acc[i][j] = __builtin_amdgcn_mfma_f32_16x16x32_f16(af[i][1], b0[j][1], acc[i][j], 0, 0, 0);
      }
    __builtin_amdgcn_s_setprio(0);
    __builtin_amdgcn_s_barrier();
    __builtin_amdgcn_sched_barrier(0);

    // ---- phase 2: (mq0, nh1)
#pragma unroll
    for (int j = 0; j < 2; j++) {
      b1[j][0] = *(const v8h*)&sB[brow + 2048 + j * 1024 + sl0];
      b1[j][1] = *(const v8h*)&sB[brow + 2048 + j * 1024 + sl1];
    }
    __builtin_amdgcn_s_barrier();
    asm volatile("s_waitcnt lgkmcnt(0)" ::: "memory");
    __builtin_amdgcn_sched_barrier(0);
    __builtin_amdgcn_s_setprio(1);
#pragma unroll
    for (int i = 0; i < 4; i++)
#pragma unroll
      for (int j = 0; j < 2; j++) {
        acc[i][2 + j] = __builtin_amdgcn_mfma_f32_16x16x32_f16(af[i][0], b1[j][0], acc[i][2 + j], 0, 0, 0);
        acc[i][2 + j] = __builtin_amdgcn_mfma_f32_16x16x32_f16(af[i][1], b1[j][1], acc[i][2 + j], 0, 0, 0);
      }
    __builtin_amdgcn_s_setprio(0);
    __builtin_amdgcn_s_barrier();
    __builtin_amdgcn_sched_barrier(0);

    // ---- phase 3: (mq1, nh1)
#pragma unroll
    for (int i = 0; i < 4; i++) {
      af[i][0] = *(const v8h*)&sA[arow + 4096 + i * 1024 + sl0];
      af[i][1] = *(const v8h*)&sA[arow + 4096 + i * 1024 + sl1];
    }
    stB(kt + 2, 0);
    __builtin_amdgcn_s_barrier();
    asm volatile("s_waitcnt lgkmcnt(0)" ::: "memory");
    __builtin_amdgcn_sched_barrier(0);
    __builtin_amdgcn_s_setprio(1);
#pragma unroll
    for (int i = 0; i < 4; i++)
#pragma unroll
      for (int j = 0; j < 2; j++) {
        acc[4 + i][2 + j] = __builtin_amdgcn_mfma_f32_16x16x32_f16(af[i][0], b1[j][0], acc[4 + i][2 + j], 0, 0, 0);
        acc[4 + i][2 + j] = __builtin_amdgcn_mfma_f32_16x16x32_f16(af[i][1], b1[j][1], acc[4 + i][2 + j], 0, 0, 0);
      }
    __builtin_amdgcn_s_setprio(0);
    __builtin_amdgcn_s_barrier();
    __builtin_amdgcn_sched_barrier(0);

    // ---- phase 4: (mq1, nh0)
    stB(kt + 2, 1);
    stA(kt + 2, 0);
    __builtin_amdgcn_s_barrier();
    __builtin_amdgcn_sched_barrier(0);
    __builtin_amdgcn_s_setprio(1);
#pragma unroll
    for (int i = 0; i < 4; i++)
#pragma unroll
      for (int j = 0; j < 2; j++) {
        acc[4 + i][j] = __builtin_amdgcn_mfma_f32_16x16x32_f16(af[i][0], b0[j][0], acc[4 + i][j], 0, 0, 0);
        acc[4 + i][j] = __builtin_amdgcn_mfma_f32_16x16x32_f16(af[i][1], b0[j][1], acc[4 + i][j], 0, 0, 0);
      }
    __builtin_amdgcn_s_setprio(0);
    if (kt + 2 < 12)      { asm volatile("s_waitcnt vmcnt(6)" ::: "memory"); }
    else if (kt + 1 < 12) { asm volatile("s_waitcnt vmcnt(0)" ::: "memory"); }
    __builtin_amdgcn_s_barrier();
    __builtin_amdgcn_sched_barrier(0);
  }

  // epilogue: C/D frag mapping col = L, row = quad*4 + r
#pragma unroll
  for (int mi = 0; mi < 8; mi++) {
    const long row = m0 + wm * 128 + (mi >> 2) * 64 + (mi & 3) * 16 + quad * 4;
#pragma unroll
    for (int nj = 0; nj < 4; nj++) {
      const long col = n0 + wn * 64 + nj * 16 + L;
#pragma unroll
      for (int r = 0; r < 4; r++)
        QK[(row + r) * 1536 + col] = f2h(acc[mi][nj][r]);
    }
  }
}

// ---------------------------------------------------------------------------
// f16 GEMM, m97 recipe (output projection): C[m,n] = sum_k A[m,k]*Bw[n,k],
// 128x128 tile, BK=32, f32 store. Grid (6,64) = 384 blocks, 2+/CU (8KB LDS).
// Measured faster than the 96-block 256^2 variant (R5 vs R6 A/B: -4 us).
// ---------------------------------------------------------------------------
__global__ __launch_bounds__(256, 2)
void gemm_proj_kernel(const unsigned short* __restrict__ A,
                      const unsigned short* __restrict__ Bw,
                      float* __restrict__ C) {
  __shared__ unsigned short As[4096];
  __shared__ unsigned short Bs[4096];

  const int t    = threadIdx.x;
  const int ln   = t & 63;
  const int wv   = t >> 6;
  const int quad = ln >> 4;
  const int L    = ln & 15;
  const int wm   = (wv >> 1) * 64;
  const int wn   = (wv & 1) * 64;
  const long m0  = (long)blockIdx.y * 128;
  const long n0  = (long)blockIdx.x * 128;

  v4f acc[4][4];
#pragma unroll
  for (int i = 0; i < 4; i++)
#pragma unroll
    for (int j = 0; j < 4; j++) acc[i][j] = (v4f){0.f, 0.f, 0.f, 0.f};

  const int ar = t >> 2;
  const int ac = (t & 3) * 8;
  const unsigned short* Ag = A + (m0 + ar) * 768 + ac;
  const unsigned short* Bg = Bw + (n0 + ar) * 768 + ac;
  unsigned short* la = &As[t * 8];
  unsigned short* lb = &Bs[t * 8];
  const long rowskip = 64L * 768;

  for (int k0 = 0; k0 < 768; k0 += 32) {
    gl_lds16(Ag + k0, la);
    gl_lds16(Ag + rowskip + k0, la + 2048);
    gl_lds16(Bg + k0, lb);
    gl_lds16(Bg + rowskip + k0, lb + 2048);
    __syncthreads();

    v8h af[4], bfr[4];
#pragma unroll
    for (int i = 0; i < 4; i++)
      af[i] = *(const v8h*)(&As[(wm + i * 16 + L) * 32 + quad * 8]);
#pragma unroll
    for (int j = 0; j < 4; j++)
      bfr[j] = *(const v8h*)(&Bs[(wn + j * 16 + L) * 32 + quad * 8]);
#pragma unroll
    for (int i = 0; i < 4; i++)
#pragma unroll
      for (int j = 0; j < 4; j++)
        acc[i][j] = __builtin_amdgcn_mfma_f32_16x16x32_f16(af[i], bfr[j], acc[i][j], 0, 0, 0);
    __syncthreads();
  }

#pragma unroll
  for (int i = 0; i < 4; i++)
#pragma unroll
    for (int j = 0; j < 4; j++)
#pragma unroll
      for (int r = 0; r < 4; r++) {
        long row = m0 + wm + i * 16 + quad * 4 + r;
        long col = n0 + wn + j * 16 + L;
        C[row * 768 + col] = acc[i][j][r];
      }
}

// ---------------------------------------------------------------------------
// COMBINED score + V-projection, 256^2 tiles, 8-phase schedule. Grid (528, 1):
//   x < 96  : V-projection -> VT transposed [d][kv]. NT=12.
//   x >= 96 : score 256-tile -> four 128^2 sub-tiles into packed lower-tri Sc
//             (raw unscaled scores). NT=4.
// Monolithic body (no device-fn factoring): acc[8][4] + staging state must
// fit 128 VGPRs; R12's factored/chained variant spilled to scratch (5x WRITE).
// ---------------------------------------------------------------------------
__global__ __launch_bounds__(512, 2)
void scv8_kernel(const unsigned short* __restrict__ QK,
                 const unsigned short* __restrict__ Xb,
                 const unsigned short* __restrict__ Wq,
                 unsigned short* __restrict__ Sc,
                 unsigned short* __restrict__ VT) {
  __shared__ unsigned short sm[65536];  // 128 KB
  const int t    = (int)threadIdx.x;
  const int ln   = t & 63;
  const int wv   = t >> 6;
  const int quad = ln >> 4;
  const int L    = ln & 15;
  const int wm   = wv >> 2;
  const int wn   = wv & 3;

  const int x = (int)blockIdx.x;
  const bool isV = (x < 96);
  int NT, Ihi = 0, Jhi = 0, bh = 0, mt = 0, nt = 0;
  const unsigned short* Abase;
  const unsigned short* Bbase;
  long astr, bstr;

  if (isV) {
    mt = x & 31;
    nt = x >> 5;
    Abase = Xb + (long)mt * 256 * 768;
    Bbase = Wq + (long)(1536 + nt * 256) * 768;
    astr = 768; bstr = 768; NT = 12;
  } else {
    int s = x - 96;
    bh = s / 36;
    int slot = s % 36;
    while (slot >= Ihi + 1) { slot -= Ihi + 1; Ihi++; }
    Jhi = slot;
    const int b = bh / 3, h = bh % 3;
    Abase = QK + ((long)b * 2048 + Ihi * 256) * 1536 + h * 256;
    Bbase = QK + ((long)b * 2048 + Jhi * 256) * 1536 + 768 + h * 256;
    astr = 1536; bstr = 1536; NT = 4;
  }

  const int srow = t >> 3;
  const int scol = ((t & 7) ^ (srow & 7)) * 8;
  const unsigned short* Ath = Abase + (long)srow * astr + scol;
  const unsigned short* Bth = Bbase + (long)srow * bstr + scol;
  unsigned short* lth = &sm[t * 8];

  const int l7   = L & 7;
  const int sl0  = ((0 + quad) ^ l7) * 8;
  const int sl1  = ((4 + quad) ^ l7) * 8;
  const int arow = (wm * 128 + L) * 64;
  const int brow = (wn * 64 + L) * 64;

  v4f acc[8][4];
#pragma unroll
  for (int i = 0; i < 8; i++)
#pragma unroll
    for (int j = 0; j < 4; j++) acc[i][j] = (v4f){0.f, 0.f, 0.f, 0.f};

  auto stA = [&](int tile, int h) {
    if (tile >= NT) return;
    const unsigned short* g = Ath + (long)(h * 128) * astr + tile * 64;
    unsigned short* l = lth + (tile & 1) * 32768 + h * 8192;
    gl_lds16(g, l);
    gl_lds16(g + 64 * astr, l + 4096);
  };
  auto stB = [&](int tile, int h) {
    if (tile >= NT) return;
    const unsigned short* g = Bth + (long)(h * 128) * bstr + tile * 64;
    unsigned short* l = lth + (tile & 1) * 32768 + 16384 + h * 8192;
    gl_lds16(g, l);
    gl_lds16(g + 64 * bstr, l + 4096);
  };

  stB(0, 0); stB(0, 1); stA(0, 0); stA(0, 1);
  stB(1, 0); stB(1, 1); stA(1, 0);
  asm volatile("s_waitcnt vmcnt(6)" ::: "memory");
  __builtin_amdgcn_s_barrier();
  __builtin_amdgcn_sched_barrier(0);

#pragma unroll 2
  for (int kt = 0; kt < NT; ++kt) {
    const unsigned short* sA = &sm[(kt & 1) * 32768];
    const unsigned short* sB = sA + 16384;
    v8h af[4][2], b0[2][2], b1[2][2];

#pragma unroll
    for (int i = 0; i < 4; i++) {
      af[i][0] = *(const v8h*)&sA[arow + i * 1024 + sl0];
      af[i][1] = *(const v8h*)&sA[arow + i * 1024 + sl1];
    }
#pragma unroll
    for (int j = 0; j < 2; j++) {
      b0[j][0] = *(const v8h*)&sB[brow + j * 1024 + sl0];
      b0[j][1] = *(const v8h*)&sB[brow + j * 1024 + sl1];
    }
    stA(kt + 1, 1);
    __builtin_amdgcn_s_barrier();
    asm volatile("s_waitcnt lgkmcnt(0)" ::: "memory");
    __builtin_amdgcn_sched_barrier(0);
    __builtin_amdgcn_s_setprio(1);
#pragma unroll
    for (int i = 0; i < 4; i++)
#pragma unroll
      for (int j = 0; j < 2; j++) {
        acc[i][j] = __builtin_amdgcn_mfma_f32_16x16x32_f16(af[i][0], b0[j][0], acc[i][j], 0, 0, 0);
        acc[i][j] = __builtin_amdgcn_mfma_f32_16x16x32_f16(af[i][1], b0[j][1], acc[i][j], 0, 0, 0);
      }
    __builtin_amdgcn_s_setprio(0);
    __builtin_amdgcn_s_barrier();
    __builtin_amdgcn_sched_barrier(0);

#pragma unroll
    for (int j = 0; j < 2; j++) {
      b1[j][0] = *(const v8h*)&sB[brow + 2048 + j * 1024 + sl0];
      b1[j][1] = *(const v8h*)&sB[brow + 2048 + j * 1024 + sl1];
    }
    __builtin_amdgcn_s_barrier();
    asm volatile("s_waitcnt lgkmcnt(0)" ::: "memory");
    __builtin_amdgcn_sched_barrier(0);
    __builtin_amdgcn_s_setprio(1);
#pragma unroll
    for (int i = 0; i < 4; i++)
#pragma unroll
      for (int j = 0; j < 2; j++) {
        acc[i][2 + j] = __builtin_amdgcn_mfma_f32_16x16x32_f16(af[i][0], b1[j][0], acc[i][2 + j], 0, 0, 0);
        acc[i][2 + j] = __builtin_amdgcn_mfma_f32_16x16x32_f16(af[i][1], b1[j][1], acc[i][2 + j], 0, 0, 0);
      }
    __builtin_amdgcn_s_setprio(0);
    __builtin_amdgcn_s_barrier();
    __builtin_amdgcn_sched_barrier(0);

#pragma unroll
    for (int i = 0; i < 4; i++) {
      af[i][0] = *(const v8h*)&sA[arow + 4096 + i * 1024 + sl0];
      af[i][1] = *(const v8h*)&sA[arow + 4096 + i * 1024 + sl1];
    }
    stB(kt + 2, 0);
    __builtin_amdgcn_s_barrier();
    asm volatile("s_waitcnt lgkmcnt(0)" ::: "memory");
    __builtin_amdgcn_sched_barrier(0);
    __builtin_amdgcn_s_setprio(1);
#pragma unroll
    for (int i = 0; i < 4; i++)
#pragma unroll
      for (int j = 0; j < 2; j++) {
        acc[4 + i][2 + j] = __builtin_amdgcn_mfma_f32_16x16x32_f16(af[i][0], b1[j][0], acc[4 + i][2 + j], 0, 0, 0);
        acc[4 + i][2 + j] = __builtin_amdgcn_mfma_f32_16x16x32_f16(af[i][1], b1[j][1], acc[4 + i][2 + j], 0, 0, 0);
      }
    __builtin_amdgcn_s_setprio(0);
    __builtin_amdgcn_s_barrier();
    __builtin_amdgcn_sched_barrier(0);

    stB(kt + 2, 1);
    stA(kt + 2, 0);
    __builtin_amdgcn_s_barrier();
    __builtin_amdgcn_sched_barrier(0);
    __builtin_amdgcn_s_setprio(1);
#pragma unroll
    for (int i = 0; i < 4; i++)
#pragma unroll
      for (int j = 0; j < 2; j++) {
        acc[4 + i][j] = __builtin_amdgcn_mfma_f32_16x16x32_f16(af[i][0], b0[j][0], acc[4 + i][j], 0, 0, 0);
        acc[4 + i][j] = __builtin_amdgcn_mfma_f32_16x16x32_f16(af[i][1], b0[j][1], acc[4 + i][j], 0, 0, 0);
      }
    __builtin_amdgcn_s_setprio(0);
    if (kt + 2 < NT)      { asm volatile("s_waitcnt vmcnt(6)" ::: "memory"); }
    else if (kt + 1 < NT) { asm volatile("s_waitcnt vmcnt(0)" ::: "memory"); }
    __builtin_amdgcn_s_barrier();
    __builtin_amdgcn_sched_barrier(0);
  }

  if (isV) {
#pragma unroll
    for (int mi = 0; mi < 8; mi++) {
      const long token = (long)mt * 256 + wm * 128 + (mi >> 2) * 64 + (mi & 3) * 16 + quad * 4;
      const int b  = (int)(token >> 11);
      const int tk = (int)(token & 2047);
#pragma unroll
      for (int nj = 0; nj < 4; nj++) {
        const int colp = nt * 256 + wn * 64 + nj * 16 + L;
        const int h    = colp >> 8;
        const int d    = colp & 255;
        v4u val = {f2h(acc[mi][nj][0]), f2h(acc[mi][nj][1]),
                   f2h(acc[mi][nj][2]), f2h(acc[mi][nj][3])};
        *(v4u*)(&VT[((long)(b * 3 + h) * 256 + d) * 2048 + tk]) = val;
      }
    }
  } else {
    const int di = wm;
    const int dj = wn >> 1;
    const int i128 = 2 * Ihi + di;
    const int j128 = 2 * Jhi + dj;
    if (j128 <= i128) {
      unsigned short* Sb = Sc + ((long)bh * 136 + (long)i128 * (i128 + 1) / 2 + j128) * 16384;
#pragma unroll
      for (int mi = 0; mi < 8; mi++) {
        const int subrow = (mi >> 2) * 64 + (mi & 3) * 16 + quad * 4;
#pragma unroll
        for (int nj = 0; nj < 4; nj++) {
          const int subcol = (wn & 1) * 64 + nj * 16 + L;
#pragma unroll
          for (int r = 0; r < 4; r++)
            Sb[(subrow + r) * 128 + subcol] = f2h(acc[mi][nj][r]);
        }
      }
    }
  }
}

// ---------------------------------------------------------------------------
// FUSED online-softmax + PV + store (LDS-staged V, TRIPLE-buffered, ONE
// barrier per step) + DEFER-MAX (T13, THR=8). Grid (16, 12), 512 thr =
// 8 waves; pair (p, 15-p) -> 17 steps balanced.
// ---------------------------------------------------------------------------
__global__ __launch_bounds__(512, 1)
void pvf_kernel(const unsigned short* __restrict__ Sc,
                const unsigned short* __restrict__ VT,
                unsigned short* __restrict__ AO) {
  __shared__ unsigned short sm[49152];  // 3 x 32KB V triple-buffer
  __shared__ float fbuf[128];           // per-wave 16-float alpha/inv slices

  const int t    = (int)threadIdx.x;
  const int ln   = t & 63;
  const int wv   = t >> 6;     // 0..7
  const int quad = ln >> 4;
  const int L    = ln & 15;

  const int p  = (int)blockIdx.x >> 1;
  const int nh = (int)blockIdx.x & 1;
  const int bh = (int)blockIdx.y;
  const int b  = bh / 3, h = bh % 3;

  const unsigned short* VTb = VT + ((long)(bh * 256 + nh * 128)) * 2048;
  const int rloc = wv * 16 + L;  // local Q-row this lane owns for softmax

  auto stageV = [&](int jj, unsigned short* base) {
#pragma unroll
    for (int pp = 0; pp < 4; pp++) {
      const int sidx = pp * 512 + t;        // 0..2047
      const int d    = sidx >> 4;
      const int ph   = sidx & 15;
      gl_lds16(VTb + (long)d * 2048 + jj * 128 + ((ph ^ (d & 7)) * 8),
               base + sidx * 8);
    }
  };

  for (int sel = 0; sel < 2; ++sel) {
    const int i = sel ? (15 - p) : p;
    const long Sbase = ((long)bh * 136 + (long)i * (i + 1) / 2) * 16384;

    v4f acc[8];
#pragma unroll
    for (int n = 0; n < 8; n++) acc[n] = (v4f){0.f, 0.f, 0.f, 0.f};
    float m_run = -1e30f, l_run = 0.f;

    // prologue: S(0) -> regs, V(0) -> buf0, V(1) -> buf1
    v8u s_cur[4], s_nxt[4];
    {
      const unsigned short* Sp = Sc + Sbase + (long)rloc * 128;
#pragma unroll
      for (int ks = 0; ks < 4; ks++)
        s_cur[ks] = *(const v8u*)(Sp + ks * 32 + quad * 8);
      __builtin_amdgcn_sched_barrier(0);
      stageV(0, &sm[0]);
      if (i >= 1) stageV(1, &sm[16384]);
      __builtin_amdgcn_sched_barrier(0);
    }

    for (int j = 0; j <= i; ++j) {
      const bool last = (j == i);  // wave-uniform
      if (!last) {
        const unsigned short* Sp = Sc + Sbase + (long)(j + 1) * 16384 + (long)rloc * 128;
#pragma unroll
        for (int ks = 0; ks < 4; ks++)
          s_nxt[ks] = *(const v8u*)(Sp + ks * 32 + quad * 8);
      }
      __builtin_amdgcn_sched_barrier(0);
      // counted wait: V(j) drained before signaling via barrier
      if (last)        { asm volatile("s_waitcnt vmcnt(0)" ::: "memory"); }
      else if (j == 0) { asm volatile("s_waitcnt vmcnt(8)" ::: "memory"); }
      else             { asm volatile("s_waitcnt vmcnt(12)" ::: "memory"); }
      __builtin_amdgcn_s_barrier();
      __builtin_amdgcn_sched_barrier(0);
      // stage V(j+2) AFTER the barrier: its target buf was last read at
      // step j-1, which every wave completed before this barrier.
      if (j + 2 <= i) stageV(j + 2, &sm[((j + 2) % 3) * 16384]);
      __builtin_amdgcn_sched_barrier(0);

      // ---- online softmax on s_cur (raw scores * 1/16) ----
      float pv[4][8];
      float mx = -1e30f;
      if (last) {  // diagonal tile: causal mask c <= r (local)
#pragma unroll
        for (int ks = 0; ks < 4; ks++)
#pragma unroll
          for (int e = 0; e < 8; e++) {
            const bool valid = (ks * 32 + quad * 8 + e) <= rloc;
            const float f = valid ? h2f(s_cur[ks][e]) * 0.0625f : -1e30f;
            pv[ks][e] = f;
            mx = fmaxf(mx, f);
          }
      } else {
#pragma unroll
        for (int ks = 0; ks < 4; ks++)
#pragma unroll
          for (int e = 0; e < 8; e++) {
            const float f = h2f(s_cur[ks][e]) * 0.0625f;
            pv[ks][e] = f;
            mx = fmaxf(mx, f);
          }
      }
      mx = fmaxf(mx, __shfl_xor(mx, 16));
      mx = fmaxf(mx, __shfl_xor(mx, 32));

      // defer-max: keep old running max if growth <= 8 (wave-uniform)
      const bool keepm = __all(mx <= m_run + 8.f);
      float alpha = 1.f;
      if (!keepm) {
        const float m_new = fmaxf(m_run, mx);
        alpha = __expf(m_run - m_new);
        m_run = m_new;
      }

      float sum = 0.f;
      v8h pa[4];
#pragma unroll
      for (int ks = 0; ks < 4; ks++) {
        v8h ph16;
#pragma unroll
        for (int e = 0; e < 8; e++) {
          const float pe = __expf(pv[ks][e] - m_run);  // masked -> exp(-huge)=0
          sum += pe;
          ph16[e] = (_Float16)pe;
        }
        pa[ks] = ph16;
      }
      sum += __shfl_xor(sum, 16);
      sum += __shfl_xor(sum, 32);

      if (keepm) {
        l_run = l_run + sum;
      } else {
        l_run = l_run * alpha + sum;
        // alpha transpose: P-row layout (row=L) -> acc-row layout (quad*4+r)
        if (quad == 0) fbuf[wv * 16 + L] = alpha;
        asm volatile("s_waitcnt lgkmcnt(0)" ::: "memory");
        __builtin_amdgcn_sched_barrier(0);
        const float a0 = fbuf[wv * 16 + quad * 4 + 0];
        const float a1 = fbuf[wv * 16 + quad * 4 + 1];
        const float a2 = fbuf[wv * 16 + quad * 4 + 2];
        const float a3 = fbuf[wv * 16 + quad * 4 + 3];
#pragma unroll
        for (int n = 0; n < 8; n++) {
          acc[n][0] *= a0; acc[n][1] *= a1; acc[n][2] *= a2; acc[n][3] *= a3;
        }
      }

      // ---- PV MFMA from swizzled LDS buf j%3 (no trailing barrier) ----
      const unsigned short* vb = &sm[(j % 3) * 16384];
      const int dx = L & 7;  // (nfc*16+L)&7 == L&7
#pragma unroll
      for (int nfc = 0; nfc < 8; nfc++) {
        const int dbase = (nfc * 16 + L) * 128;
        v8h v0 = *(const v8h*)&vb[dbase + ((0 + quad) ^ dx) * 8];
        v8h v1 = *(const v8h*)&vb[dbase + ((4 + quad) ^ dx) * 8];
        v8h v2 = *(const v8h*)&vb[dbase + ((8 + quad) ^ dx) * 8];
        v8h v3 = *(const v8h*)&vb[dbase + ((12 + quad) ^ dx) * 8];
        acc[nfc] = __builtin_amdgcn_mfma_f32_16x16x32_f16(pa[0], v0, acc[nfc], 0, 0, 0);
        acc[nfc] = __builtin_amdgcn_mfma_f32_16x16x32_f16(pa[1], v1, acc[nfc], 0, 0, 0);
        acc[nfc] = __builtin_amdgcn_mfma_f32_16x16x32_f16(pa[2], v2, acc[nfc], 0, 0, 0);
        acc[nfc] = __builtin_amdgcn_mfma_f32_16x16x32_f16(pa[3], v3, acc[nfc], 0, 0, 0);
      }

#pragma unroll
      for (int ks = 0; ks < 4; ks++) s_cur[ks] = s_nxt[ks];
    }

    // finalize: divide by l (transpose inv like alpha) and store f16 to AO
    const float inv = 1.0f / l_run;
    if (quad == 0) fbuf[wv * 16 + L] = inv;
    asm volatile("s_waitcnt lgkmcnt(0)" ::: "memory");
    __builtin_amdgcn_sched_barrier(0);
    const float i0 = fbuf[wv * 16 + quad * 4 + 0];
    const float i1 = fbuf[wv * 16 + quad * 4 + 1];
    const float i2 = fbuf[wv * 16 + quad * 4 + 2];
    const float i3 = fbuf[wv * 16 + quad * 4 + 3];

    unsigned short* Ob = AO + ((long)b * 2048 + (long)i * 128 + wv * 16 + quad * 4) * 768
                            + h * 256 + nh * 128 + L;
#pragma unroll
    for (int n = 0; n < 8; n++) {
      Ob[0 * 768 + n * 16] = f2h(acc[n][0] * i0);
      Ob[1 * 768 + n * 16] = f2h(acc[n][1] * i1);
      Ob[2 * 768 + n * 16] = f2h(acc[n][2] * i2);
      Ob[3 * 768 + n * 16] = f2h(acc[n][3] * i3);
    }
    __builtin_amdgcn_s_barrier();  // all V-buf reads done before next sel
  }
}

// ---------------------------------------------------------------------------
extern "C" void kernel_launch(void* const* d_in, const int* in_sizes, int n_in,
                              void* d_out, int out_size, void* d_ws, size_t ws_size,
                              hipStream_t stream) {
  const float* X     = (const float*)d_in[0];  // [4,2048,768] f32
  const float* Wqkv  = (const float*)d_in[1];  // [2304,768]   f32
  const float* Wproj = (const float*)d_in[2];  // [768,768]    f32
  float* out = (float*)d_out;                  // [4,2048,768] f32

  const size_t SZ_QK = (size_t)8192 * 1536 * 2;       // 25.2 MB
  const size_t SZ_VT = (size_t)3072 * 2048 * 2;       // 12.6 MB
  const size_t SZ_SC = (size_t)12 * 136 * 16384 * 2;  // 53.5 MB
  const size_t SZ_AO = (size_t)8192 * 768 * 2;        // 12.6 MB
  const size_t SZ_WQ = (size_t)2304 * 768 * 2;        //  3.5 MB

  char* ws = (char*)d_ws;
  unsigned short* QKb = (unsigned short*)ws;
  unsigned short* VTb = (unsigned short*)(ws + SZ_QK);
  unsigned short* Scb = (unsigned short*)(ws + SZ_QK + SZ_VT);
  unsigned short* AOb = (unsigned short*)(ws + SZ_QK + SZ_VT + SZ_SC);
  unsigned short* Xb  = AOb;  // alias: Xb dead after scv8; AO written by pvf (later)
  unsigned short* Wqb = (unsigned short*)(ws + SZ_QK + SZ_VT + SZ_SC + SZ_AO);
  unsigned short* Wpb = (unsigned short*)(ws + SZ_QK + SZ_VT + SZ_SC + SZ_AO + SZ_WQ);

  dim3 blk(256, 1, 1);
  // 0) one-time f32 -> f16 conversions (single launch)
  cvt3_kernel<<<dim3(4224, 1, 1), blk, 0, stream>>>(X, Wqkv, Wproj, Xb, Wqb, Wpb);
  // 1) Q,K projection, 256^2 8-phase schedule, one round
  qkv8_kernel<<<dim3(6, 32, 1), dim3(512, 1, 1), 0, stream>>>(Xb, Wqb, QKb);
  // 2) score tiles + V projection, 256^2 8-phase, ONE dispatch (V-first LPT)
  scv8_kernel<<<dim3(528, 1, 1), dim3(512, 1, 1), 0, stream>>>(QKb, Xb, Wqb, Scb, VTb);
  // 3) fused online-softmax + PV + store (triple-buffer V, defer-max)
  pvf_kernel<<<dim3(16, 12, 1), dim3(512, 1, 1), 0, stream>>>(Scb, VTb, AOb);
  // 4) output projection, m97 128^2, 384 blocks 2/CU (measured faster, R5)
  gemm_proj_kernel<<<dim3(6, 64, 1), blk, 0, stream>>>(AOb, Wpb, out);
}